// Round 1
// baseline (1742.667 us; speedup 1.0000x reference)
//
#include <hip/hip_runtime.h>
#include <math.h>

// Problem constants
#define BB  4
#define CCH 128
#define HCH 64
#define NN  65536            // H*W

constexpr float EPS_   = 1e-5f;
constexpr float SCALE_ = 1.0f / 4194304.0f;   // 1/(N*HC) = 1/(65536*64), exact pow2

#define LSTR 66              // padded LDS row stride (floats) for 64-wide tiles

// workspace layout (float offsets)
#define OFF_G    0           // [B][64][64]  Gram of x2            (zeroed, atomically accumulated)
#define OFF_CG   16384       // [B][64][64]  cross-Gram X1*Y2^T    (zeroed, atomically accumulated)
#define OFF_PT   32768       // [B][64][64]  P^T   (PT[c*64+o] = P[o][c])
#define OFF_CAT  49152       // [B][64][64]  cattn^T (CT[k*64+q] = cattn[q][k])
#define OFF_W1T  65536       // [64][64]     out1_w^T
#define OFF_WOT  69632       // [128][128]   out_w^T
#define WS_FLOATS 86016

// ---------------------------------------------------------------- helpers

__device__ __forceinline__ void softmax_row64(float* row) {
  float mx = -1e30f;
  for (int k = 0; k < 64; ++k) mx = fmaxf(mx, row[k] * SCALE_);
  float s = 0.f;
  for (int k = 0; k < 64; ++k) {
    float e = __expf(row[k] * SCALE_ - mx);
    row[k] = e;
    s += e;
  }
  float inv = 1.0f / s;
  for (int k = 0; k < 64; ++k) row[k] *= inv;
}

// Co[i][j] = sum_m A[i][m] * B[m][j]   (64x64x64, 256 threads, 4x4 per thread)
__device__ __forceinline__ void mm64_nn(const float* A, const float* Bm, float* Co,
                                        int ti, int tj) {
  float acc[4][4];
#pragma unroll
  for (int a = 0; a < 4; ++a)
#pragma unroll
    for (int c = 0; c < 4; ++c) acc[a][c] = 0.f;
  for (int m = 0; m < 64; ++m) {
    float av[4], bv[4];
#pragma unroll
    for (int a = 0; a < 4; ++a) av[a] = A[(4 * ti + a) * LSTR + m];
#pragma unroll
    for (int c = 0; c < 4; ++c) bv[c] = Bm[m * LSTR + 4 * tj + c];
#pragma unroll
    for (int a = 0; a < 4; ++a)
#pragma unroll
      for (int c = 0; c < 4; ++c) acc[a][c] = fmaf(av[a], bv[c], acc[a][c]);
  }
#pragma unroll
  for (int a = 0; a < 4; ++a)
#pragma unroll
    for (int c = 0; c < 4; ++c) Co[(4 * ti + a) * LSTR + 4 * tj + c] = acc[a][c];
}

// Co[i][j] = sum_m A[i][m] * B[j][m]
__device__ __forceinline__ void mm64_nt(const float* A, const float* Bm, float* Co,
                                        int ti, int tj) {
  float acc[4][4];
#pragma unroll
  for (int a = 0; a < 4; ++a)
#pragma unroll
    for (int c = 0; c < 4; ++c) acc[a][c] = 0.f;
  for (int m = 0; m < 64; ++m) {
    float av[4], bv[4];
#pragma unroll
    for (int a = 0; a < 4; ++a) av[a] = A[(4 * ti + a) * LSTR + m];
#pragma unroll
    for (int c = 0; c < 4; ++c) bv[c] = Bm[(4 * tj + c) * LSTR + m];
#pragma unroll
    for (int a = 0; a < 4; ++a)
#pragma unroll
      for (int c = 0; c < 4; ++c) acc[a][c] = fmaf(av[a], bv[c], acc[a][c]);
  }
#pragma unroll
  for (int a = 0; a < 4; ++a)
#pragma unroll
    for (int c = 0; c < 4; ++c) Co[(4 * ti + a) * LSTR + 4 * tj + c] = acc[a][c];
}

__device__ __forceinline__ void ld64(float* dst, const float* src, int tid) {
  for (int i = tid; i < 4096; i += 256) dst[(i >> 6) * LSTR + (i & 63)] = src[i];
}

// ---------------------------------------------------------------- kernels

// transpose out1_w and out_w into ws (so per-pixel matvecs read contiguous columns)
__global__ void k_transpose(const float* __restrict__ w1,
                            const float* __restrict__ wo,
                            float* __restrict__ ws) {
  int tid = blockIdx.x * blockDim.x + threadIdx.x;
  int stride = gridDim.x * blockDim.x;
  for (int i = tid; i < 64 * 64; i += stride) {
    int o = i >> 6, c = i & 63;
    ws[OFF_W1T + c * 64 + o] = w1[o * 64 + c];
  }
  for (int i = tid; i < 128 * 128; i += stride) {
    int o = i >> 7, c = i & 127;
    ws[OFF_WOT + c * 128 + o] = wo[o * 128 + c];
  }
}

// G[b] = X2_b @ X2_b^T    (LDS-tiled, 4x4 register tiling, atomic combine)
__global__ __launch_bounds__(256) void k_gram(const float* __restrict__ x,
                                              float* __restrict__ ws) {
  __shared__ float tile[128 * LSTR];   // [pixel][ch], ~33.8 KB
  const int tid = threadIdx.x;
  const int b = blockIdx.y;
  const int ti = tid & 15, tj = tid >> 4;
  const float* x2 = x + ((size_t)b * CCH + HCH) * NN;

  float acc[4][4];
#pragma unroll
  for (int a = 0; a < 4; ++a)
#pragma unroll
    for (int c = 0; c < 4; ++c) acc[a][c] = 0.f;

  for (int t = blockIdx.x; t < NN / 128; t += gridDim.x) {
    const int base = t * 128;
    for (int i = tid; i < 128 * 64; i += 256) {
      int ch = i >> 7, p = i & 127;
      tile[p * LSTR + ch] = x2[(size_t)ch * NN + base + p];
    }
    __syncthreads();
    for (int p = 0; p < 128; ++p) {
      float av[4], bv[4];
#pragma unroll
      for (int a = 0; a < 4; ++a) av[a] = tile[p * LSTR + 4 * ti + a];
#pragma unroll
      for (int c = 0; c < 4; ++c) bv[c] = tile[p * LSTR + 4 * tj + c];
#pragma unroll
      for (int a = 0; a < 4; ++a)
#pragma unroll
        for (int c = 0; c < 4; ++c) acc[a][c] = fmaf(av[a], bv[c], acc[a][c]);
    }
    __syncthreads();
  }
  float* G = ws + OFF_G + b * 4096;
#pragma unroll
  for (int a = 0; a < 4; ++a)
#pragma unroll
    for (int c = 0; c < 4; ++c)
      atomicAdd(&G[(4 * ti + a) * 64 + (4 * tj + c)], acc[a][c]);
}

// per batch: S = Wq G Wk^T ; attn = softmax(S*scale) ; M = attn Wv ;
// P = O2a + O2b M ; store P^T
__global__ __launch_bounds__(256) void k_attn(const float* __restrict__ ln2_w,
                                              const float* __restrict__ out2_w,
                                              float* __restrict__ ws) {
  __shared__ float LA[64 * LSTR], LB[64 * LSTR], LC[64 * LSTR];
  const int b = blockIdx.x, tid = threadIdx.x;
  const int ti = tid & 15, tj = tid >> 4;
  const float* G = ws + OFF_G + b * 4096;

  ld64(LA, ln2_w, tid);              // Wq = ln2_w rows 0..63
  ld64(LB, G, tid);
  __syncthreads();
  mm64_nn(LA, LB, LC, ti, tj);       // LC = Wq @ G
  __syncthreads();
  ld64(LA, ln2_w + 4096, tid);       // Wk
  __syncthreads();
  mm64_nt(LC, LA, LB, ti, tj);       // LB = S = (WqG) @ Wk^T
  __syncthreads();
  if (tid < 64) softmax_row64(LB + tid * LSTR);   // attn in LB
  __syncthreads();
  ld64(LA, ln2_w + 8192, tid);       // Wv
  __syncthreads();
  mm64_nn(LB, LA, LC, ti, tj);       // LC = M = attn @ Wv
  __syncthreads();
  for (int i = tid; i < 4096; i += 256)            // LA = O2b = out2_w[:,64:]
    LA[(i >> 6) * LSTR + (i & 63)] = out2_w[(i >> 6) * 128 + 64 + (i & 63)];
  __syncthreads();
  float* PT = ws + OFF_PT + b * 4096;
#pragma unroll
  for (int a = 0; a < 4; ++a) {
#pragma unroll
    for (int c = 0; c < 4; ++c) {
      int o = 4 * ti + a, j = 4 * tj + c;
      float s = out2_w[o * 128 + j];               // O2a[o][j]
      for (int m = 0; m < 64; ++m) s = fmaf(LA[o * LSTR + m], LC[m * LSTR + j], s);
      PT[j * 64 + o] = s;                          // transposed store
    }
  }
}

// per pixel: y2 = LN(P x2); accumulate CG[b] += x1 (outer) y2
__global__ __launch_bounds__(256) void k_cgram(const float* __restrict__ x,
                                               const float* __restrict__ g2,
                                               const float* __restrict__ b2,
                                               float* __restrict__ ws) {
  __shared__ float x1t[64 * LSTR];
  __shared__ float y2t[64 * LSTR];
  const int tid = threadIdx.x;
  const int b = blockIdx.y;
  const int ti = tid & 15, tj = tid >> 4;
  const float* PT = ws + OFF_PT + b * 4096;
  const float* x1p = x + (size_t)b * CCH * NN;
  const float* x2p = x1p + (size_t)HCH * NN;

  float acc[4][4];
#pragma unroll
  for (int a = 0; a < 4; ++a)
#pragma unroll
    for (int c = 0; c < 4; ++c) acc[a][c] = 0.f;

  for (int t = blockIdx.x; t < NN / 256; t += gridDim.x) {
    const int n = t * 256 + tid;
    // per-thread: z = P @ x2  (weights via uniform addresses -> s_load)
    float z[64];
#pragma unroll
    for (int o = 0; o < 64; ++o) z[o] = 0.f;
    for (int c = 0; c < 64; ++c) {
      float xc = x2p[(size_t)c * NN + n];
#pragma unroll
      for (int o = 0; o < 64; ++o) z[o] = fmaf(PT[c * 64 + o], xc, z[o]);
    }
    // LN over channels -> y2 (kept in regs)
    float m = 0.f;
#pragma unroll
    for (int o = 0; o < 64; ++o) m += z[o];
    m *= (1.0f / 64.0f);
    float v = 0.f;
#pragma unroll
    for (int o = 0; o < 64; ++o) { float d = z[o] - m; v = fmaf(d, d, v); }
    v *= (1.0f / 64.0f);
    float r = rsqrtf(v + EPS_);
#pragma unroll
    for (int o = 0; o < 64; ++o) z[o] = (z[o] - m) * r * g2[o] + b2[o];

    // quarter-tiles of 64 pixels: stage x1 + y2, then cooperative cross-Gram
    for (int q4 = 0; q4 < 4; ++q4) {
      const int pb = t * 256 + q4 * 64;
      for (int i = tid; i < 64 * 64; i += 256) {
        int ch = i >> 6, p = i & 63;
        x1t[p * LSTR + ch] = x1p[(size_t)ch * NN + pb + p];
      }
      if ((tid >> 6) == q4) {
        const int p = tid & 63;
#pragma unroll
        for (int o = 0; o < 64; ++o) y2t[p * LSTR + o] = z[o];
      }
      __syncthreads();
      for (int p = 0; p < 64; ++p) {
        float av[4], bv[4];
#pragma unroll
        for (int a = 0; a < 4; ++a) av[a] = x1t[p * LSTR + 4 * ti + a];
#pragma unroll
        for (int c = 0; c < 4; ++c) bv[c] = y2t[p * LSTR + 4 * tj + c];
#pragma unroll
        for (int a = 0; a < 4; ++a)
#pragma unroll
          for (int c = 0; c < 4; ++c) acc[a][c] = fmaf(av[a], bv[c], acc[a][c]);
      }
      __syncthreads();
    }
  }
  float* CG = ws + OFF_CG + b * 4096;
#pragma unroll
  for (int a = 0; a < 4; ++a)
#pragma unroll
    for (int c = 0; c < 4; ++c)
      atomicAdd(&CG[(4 * ti + a) * 64 + (4 * tj + c)], acc[a][c]);
}

// per batch: T = W1 @ CG ; cattn = softmax(T*scale) ; store cattn^T
__global__ __launch_bounds__(256) void k_cattn(const float* __restrict__ ln1_w,
                                               float* __restrict__ ws) {
  __shared__ float LA[64 * LSTR], LB[64 * LSTR], LC[64 * LSTR];
  const int b = blockIdx.x, tid = threadIdx.x;
  const int ti = tid & 15, tj = tid >> 4;
  ld64(LA, ln1_w, tid);
  ld64(LB, ws + OFF_CG + b * 4096, tid);
  __syncthreads();
  mm64_nn(LA, LB, LC, ti, tj);       // T = W1 @ CG
  __syncthreads();
  if (tid < 64) softmax_row64(LC + tid * LSTR);
  __syncthreads();
  float* CT = ws + OFF_CAT + b * 4096;
  for (int i = tid; i < 4096; i += 256) {
    int q = i >> 6, k = i & 63;
    CT[k * 64 + q] = LC[q * LSTR + k];
  }
}

// fused final pass: y2, corr, x1g, y1, out = relu(LN(Wo [y1;y2])) + x
// 1 thread = 1 pixel; per-thread vectors live in LDS lane-columns ([ch][tid]),
// accumulators are statically-indexed registers.
__global__ __launch_bounds__(64) void k_final(
    const float* __restrict__ x, const float* __restrict__ ws,
    const float* __restrict__ g2, const float* __restrict__ b2v,
    const float* __restrict__ g1, const float* __restrict__ b1v,
    const float* __restrict__ go, const float* __restrict__ bo,
    float* __restrict__ out) {
  __shared__ float sA[64 * 64];   // y2   [ch][tid]
  __shared__ float sB[64 * 64];   // x1g, then y1
  const int tid = threadIdx.x;
  const int b = blockIdx.y;
  const int n = blockIdx.x * 64 + tid;
  const float* PT  = ws + OFF_PT + b * 4096;
  const float* CT  = ws + OFF_CAT + b * 4096;
  const float* W1T = ws + OFF_W1T;
  const float* WOT = ws + OFF_WOT;
  const float* xb  = x + (size_t)b * CCH * NN;
  const float* x2p = xb + (size_t)HCH * NN;

  float acc[128];

  // ---- z = P @ x2
#pragma unroll
  for (int o = 0; o < 64; ++o) acc[o] = 0.f;
  for (int c = 0; c < 64; ++c) {
    float xc = x2p[(size_t)c * NN + n];
#pragma unroll
    for (int o = 0; o < 64; ++o) acc[o] = fmaf(PT[c * 64 + o], xc, acc[o]);
  }
  // ---- LN -> y2 -> sA
  {
    float m = 0.f;
#pragma unroll
    for (int o = 0; o < 64; ++o) m += acc[o];
    m *= (1.0f / 64.0f);
    float v = 0.f;
#pragma unroll
    for (int o = 0; o < 64; ++o) { float d = acc[o] - m; v = fmaf(d, d, v); }
    v *= (1.0f / 64.0f);
    float r = rsqrtf(v + EPS_);
#pragma unroll
    for (int o = 0; o < 64; ++o)
      sA[o * 64 + tid] = (acc[o] - m) * r * g2[o] + b2v[o];
  }
  // ---- c = cattn @ y2
#pragma unroll
  for (int o = 0; o < 64; ++o) acc[o] = 0.f;
  for (int k = 0; k < 64; ++k) {
    float yk = sA[k * 64 + tid];
#pragma unroll
    for (int q = 0; q < 64; ++q) acc[q] = fmaf(CT[k * 64 + q], yk, acc[q]);
  }
  // ---- corr = sigmoid(c); x1g = x1*(1+corr) -> sB
#pragma unroll
  for (int i = 0; i < 64; ++i) {
    float cr = 1.0f / (1.0f + __expf(-acc[i]));
    float x1v = xb[(size_t)i * NN + n];
    sB[i * 64 + tid] = x1v + x1v * cr;
  }
  // ---- w1 = out1_w @ x1g
#pragma unroll
  for (int o = 0; o < 64; ++o) acc[o] = 0.f;
  for (int c = 0; c < 64; ++c) {
    float xc = sB[c * 64 + tid];
#pragma unroll
    for (int o = 0; o < 64; ++o) acc[o] = fmaf(W1T[c * 64 + o], xc, acc[o]);
  }
  // ---- LN -> y1 -> sB (overwrites x1g, which is dead)
  {
    float m = 0.f;
#pragma unroll
    for (int o = 0; o < 64; ++o) m += acc[o];
    m *= (1.0f / 64.0f);
    float v = 0.f;
#pragma unroll
    for (int o = 0; o < 64; ++o) { float d = acc[o] - m; v = fmaf(d, d, v); }
    v *= (1.0f / 64.0f);
    float r = rsqrtf(v + EPS_);
#pragma unroll
    for (int o = 0; o < 64; ++o)
      sB[o * 64 + tid] = (acc[o] - m) * r * g1[o] + b1v[o];
  }
  // ---- t = out_w @ [y1; y2]
#pragma unroll
  for (int o = 0; o < 128; ++o) acc[o] = 0.f;
  for (int c = 0; c < 64; ++c) {
    float mc = sB[c * 64 + tid];
#pragma unroll
    for (int o = 0; o < 128; ++o) acc[o] = fmaf(WOT[c * 128 + o], mc, acc[o]);
  }
  for (int c = 0; c < 64; ++c) {
    float mc = sA[c * 64 + tid];
#pragma unroll
    for (int o = 0; o < 128; ++o) acc[o] = fmaf(WOT[(64 + c) * 128 + o], mc, acc[o]);
  }
  // ---- LN(128) -> relu -> + x -> store
  {
    float m = 0.f;
#pragma unroll
    for (int o = 0; o < 128; ++o) m += acc[o];
    m *= (1.0f / 128.0f);
    float v = 0.f;
#pragma unroll
    for (int o = 0; o < 128; ++o) { float d = acc[o] - m; v = fmaf(d, d, v); }
    v *= (1.0f / 128.0f);
    float r = rsqrtf(v + EPS_);
#pragma unroll
    for (int o = 0; o < 128; ++o) {
      float val = (acc[o] - m) * r * go[o] + bo[o];
      val = fmaxf(val, 0.0f);
      out[(size_t)b * CCH * NN + (size_t)o * NN + n] = val + xb[(size_t)o * NN + n];
    }
  }
}

// ---------------------------------------------------------------- launch

extern "C" void kernel_launch(void* const* d_in, const int* in_sizes, int n_in,
                              void* d_out, int out_size, void* d_ws, size_t ws_size,
                              hipStream_t stream) {
  (void)in_sizes; (void)n_in; (void)out_size; (void)ws_size;
  const float* x      = (const float*)d_in[0];
  const float* ln1_w  = (const float*)d_in[1];
  const float* ln2_w  = (const float*)d_in[2];
  const float* out1_w = (const float*)d_in[3];
  const float* out1_g = (const float*)d_in[4];
  const float* out1_b = (const float*)d_in[5];
  const float* out2_w = (const float*)d_in[6];
  const float* out2_g = (const float*)d_in[7];
  const float* out2_b = (const float*)d_in[8];
  const float* out_w  = (const float*)d_in[9];
  const float* out_g  = (const float*)d_in[10];
  const float* out_b  = (const float*)d_in[11];
  float* out = (float*)d_out;
  float* ws  = (float*)d_ws;

  // zero the two atomically-accumulated regions (G, CG)
  hipMemsetAsync(d_ws, 0, (size_t)OFF_PT * sizeof(float), stream);

  hipLaunchKernelGGL(k_transpose, dim3(16), dim3(256), 0, stream, out1_w, out_w, ws);
  hipLaunchKernelGGL(k_gram,  dim3(128, BB), dim3(256), 0, stream, x, ws);
  hipLaunchKernelGGL(k_attn,  dim3(BB), dim3(256), 0, stream, ln2_w, out2_w, ws);
  hipLaunchKernelGGL(k_cgram, dim3(128, BB), dim3(256), 0, stream, x, out2_g, out2_b, ws);
  hipLaunchKernelGGL(k_cattn, dim3(BB), dim3(256), 0, stream, ln1_w, ws);
  hipLaunchKernelGGL(k_final, dim3(NN / 64, BB), dim3(64), 0, stream,
                     x, ws, out2_g, out2_b, out1_g, out1_b, out_g, out_b, out);
}

// Round 7
// 1281.690 us; speedup vs baseline: 1.3597x; 1.3597x over previous
//
#include <hip/hip_runtime.h>
#include <math.h>

// Problem constants
#define BB  4
#define CCH 128
#define HCH 64
#define NN  65536            // H*W

constexpr float EPS_   = 1e-5f;
constexpr float SCALE_ = 1.0f / 4194304.0f;   // 1/(N*HC), exact pow2

#define LSTR 65              // odd LDS row stride -> conflict-free staging writes

// workspace layout (float offsets) -- only small matrices live in ws now
#define OFF_G    0           // [B][64][64]  Gram of x2          (zeroed, atomic)
#define OFF_CG   16384       // [B][64][64]  cross-Gram X1*Y2^T  (zeroed, atomic)
#define OFF_PT   32768       // [B][64][64]  P^T  (PT[c*64+o] = P[o][c])
#define OFF_CAT  49152       // [B][64][64]  cattn^T (CT[k*64+q] = cattn[q][k])
#define OFF_W1T  65536       // [64][64]     out1_w^T  ([c][o])
#define OFF_WOT  69632       // [128][128]   out_w^T   ([c][o])

// y2 lives in d_out channels 64..127; y1 in d_out channels 0..63 (pixel-local
// overwrite in f_out is race-free: each pixel is read+written by one wave only).

// ---------------------------------------------------------------- helpers

__device__ __forceinline__ void softmax_row64(float* row) {
  float mx = -1e30f;
  for (int k = 0; k < 64; ++k) mx = fmaxf(mx, row[k] * SCALE_);
  float s = 0.f;
  for (int k = 0; k < 64; ++k) {
    float e = __expf(row[k] * SCALE_ - mx);
    row[k] = e;
    s += e;
  }
  float inv = 1.0f / s;
  for (int k = 0; k < 64; ++k) row[k] *= inv;
}

__device__ __forceinline__ void mm64_nn(const float* A, const float* Bm, float* Co,
                                        int ti, int tj) {
  float acc[4][4];
#pragma unroll
  for (int a = 0; a < 4; ++a)
#pragma unroll
    for (int c = 0; c < 4; ++c) acc[a][c] = 0.f;
  for (int m = 0; m < 64; ++m) {
    float av[4], bv[4];
#pragma unroll
    for (int a = 0; a < 4; ++a) av[a] = A[(4 * ti + a) * LSTR + m];
#pragma unroll
    for (int c = 0; c < 4; ++c) bv[c] = Bm[m * LSTR + 4 * tj + c];
#pragma unroll
    for (int a = 0; a < 4; ++a)
#pragma unroll
      for (int c = 0; c < 4; ++c) acc[a][c] = fmaf(av[a], bv[c], acc[a][c]);
  }
#pragma unroll
  for (int a = 0; a < 4; ++a)
#pragma unroll
    for (int c = 0; c < 4; ++c) Co[(4 * ti + a) * LSTR + 4 * tj + c] = acc[a][c];
}

__device__ __forceinline__ void mm64_nt(const float* A, const float* Bm, float* Co,
                                        int ti, int tj) {
  float acc[4][4];
#pragma unroll
  for (int a = 0; a < 4; ++a)
#pragma unroll
    for (int c = 0; c < 4; ++c) acc[a][c] = 0.f;
  for (int m = 0; m < 64; ++m) {
    float av[4], bv[4];
#pragma unroll
    for (int a = 0; a < 4; ++a) av[a] = A[(4 * ti + a) * LSTR + m];
#pragma unroll
    for (int c = 0; c < 4; ++c) bv[c] = Bm[(4 * tj + c) * LSTR + m];
#pragma unroll
    for (int a = 0; a < 4; ++a)
#pragma unroll
      for (int c = 0; c < 4; ++c) acc[a][c] = fmaf(av[a], bv[c], acc[a][c]);
  }
#pragma unroll
  for (int a = 0; a < 4; ++a)
#pragma unroll
    for (int c = 0; c < 4; ++c) Co[(4 * ti + a) * LSTR + 4 * tj + c] = acc[a][c];
}

__device__ __forceinline__ void ld64(float* dst, const float* src, int tid) {
  for (int i = tid; i < 4096; i += 256) dst[(i >> 6) * LSTR + (i & 63)] = src[i];
}

// ---------------------------------------------------------------- small kernels

__global__ void k_transpose(const float* __restrict__ w1,
                            const float* __restrict__ wo,
                            float* __restrict__ ws) {
  int tid = blockIdx.x * blockDim.x + threadIdx.x;
  int stride = gridDim.x * blockDim.x;
  for (int i = tid; i < 64 * 64; i += stride) {
    int o = i >> 6, c = i & 63;
    ws[OFF_W1T + c * 64 + o] = w1[o * 64 + c];
  }
  for (int i = tid; i < 128 * 128; i += stride) {
    int o = i >> 7, c = i & 127;
    ws[OFF_WOT + c * 128 + o] = wo[o * 128 + c];
  }
}

// G[b] = X2_b @ X2_b^T
__global__ __launch_bounds__(256) void k_gram(const float* __restrict__ x,
                                              float* __restrict__ ws) {
  __shared__ float tile[128 * LSTR];
  const int tid = threadIdx.x;
  const int b = blockIdx.y;
  const int ti = tid & 15, tj = tid >> 4;
  const float* x2 = x + ((size_t)b * CCH + HCH) * NN;

  float acc[4][4];
#pragma unroll
  for (int a = 0; a < 4; ++a)
#pragma unroll
    for (int c = 0; c < 4; ++c) acc[a][c] = 0.f;

  for (int t = blockIdx.x; t < NN / 128; t += gridDim.x) {
    const int base = t * 128;
    for (int i = tid; i < 128 * 64; i += 256) {
      int ch = i >> 7, p = i & 127;
      tile[p * LSTR + ch] = x2[(size_t)ch * NN + base + p];
    }
    __syncthreads();
    for (int p = 0; p < 128; ++p) {
      float av[4], bv[4];
#pragma unroll
      for (int a = 0; a < 4; ++a) av[a] = tile[p * LSTR + 4 * ti + a];
#pragma unroll
      for (int c = 0; c < 4; ++c) bv[c] = tile[p * LSTR + 4 * tj + c];
#pragma unroll
      for (int a = 0; a < 4; ++a)
#pragma unroll
        for (int c = 0; c < 4; ++c) acc[a][c] = fmaf(av[a], bv[c], acc[a][c]);
    }
    __syncthreads();
  }
  float* G = ws + OFF_G + b * 4096;
#pragma unroll
  for (int a = 0; a < 4; ++a)
#pragma unroll
    for (int c = 0; c < 4; ++c)
      atomicAdd(&G[(4 * ti + a) * 64 + (4 * tj + c)], acc[a][c]);
}

// per batch: S = Wq G Wk^T ; attn = softmax ; M = attn Wv ; P = O2a + O2b M ; store P^T
__global__ __launch_bounds__(256) void k_attn(const float* __restrict__ ln2_w,
                                              const float* __restrict__ out2_w,
                                              float* __restrict__ ws) {
  __shared__ float LA[64 * LSTR], LB[64 * LSTR], LC[64 * LSTR];
  const int b = blockIdx.x, tid = threadIdx.x;
  const int ti = tid & 15, tj = tid >> 4;
  const float* G = ws + OFF_G + b * 4096;

  ld64(LA, ln2_w, tid);              // Wq
  ld64(LB, G, tid);
  __syncthreads();
  mm64_nn(LA, LB, LC, ti, tj);       // LC = Wq @ G
  __syncthreads();
  ld64(LA, ln2_w + 4096, tid);       // Wk
  __syncthreads();
  mm64_nt(LC, LA, LB, ti, tj);       // LB = S
  __syncthreads();
  if (tid < 64) softmax_row64(LB + tid * LSTR);
  __syncthreads();
  ld64(LA, ln2_w + 8192, tid);       // Wv
  __syncthreads();
  mm64_nn(LB, LA, LC, ti, tj);       // LC = attn @ Wv
  __syncthreads();
  for (int i = tid; i < 4096; i += 256)            // LA = O2b
    LA[(i >> 6) * LSTR + (i & 63)] = out2_w[(i >> 6) * 128 + 64 + (i & 63)];
  __syncthreads();
  float* PT = ws + OFF_PT + b * 4096;
#pragma unroll
  for (int a = 0; a < 4; ++a) {
#pragma unroll
    for (int c = 0; c < 4; ++c) {
      int o = 4 * ti + a, j = 4 * tj + c;
      float s = out2_w[o * 128 + j];               // O2a
      for (int m = 0; m < 64; ++m) s = fmaf(LA[o * LSTR + m], LC[m * LSTR + j], s);
      PT[j * 64 + o] = s;
    }
  }
}

// per batch: T = W1 @ CG ; cattn = softmax ; store cattn^T
__global__ __launch_bounds__(256) void k_cattn(const float* __restrict__ ln1_w,
                                               float* __restrict__ ws) {
  __shared__ float LA[64 * LSTR], LB[64 * LSTR], LC[64 * LSTR];
  const int b = blockIdx.x, tid = threadIdx.x;
  const int ti = tid & 15, tj = tid >> 4;
  ld64(LA, ln1_w, tid);
  ld64(LB, ws + OFF_CG + b * 4096, tid);
  __syncthreads();
  mm64_nn(LA, LB, LC, ti, tj);
  __syncthreads();
  if (tid < 64) softmax_row64(LC + tid * LSTR);
  __syncthreads();
  float* CT = ws + OFF_CAT + b * 4096;
  for (int i = tid; i < 4096; i += 256) {
    int q = i >> 6, k = i & 63;
    CT[k * 64 + q] = LC[q * LSTR + k];
  }
}

// ---------------------------------------------------------------- streaming kernels

// y2 = LN(P @ x2) per pixel -> dout channels 64..127
__global__ __launch_bounds__(256) void f_y2(const float* __restrict__ x,
                                            const float* __restrict__ ws,
                                            const float* __restrict__ g2,
                                            const float* __restrict__ b2,
                                            float* __restrict__ dout) {
  const int tid = threadIdx.x;
  const int b = blockIdx.y;
  const int n = blockIdx.x * 256 + tid;
  const float* PT  = ws + OFF_PT + b * 4096;
  const float* x2p = x + ((size_t)b * CCH + HCH) * NN;

  float z[64];
#pragma unroll
  for (int o = 0; o < 64; ++o) z[o] = 0.f;
#pragma unroll
  for (int c0 = 0; c0 < 64; c0 += 8) {
    float xc[8];
#pragma unroll
    for (int u = 0; u < 8; ++u) xc[u] = x2p[(size_t)(c0 + u) * NN + n];
#pragma unroll
    for (int u = 0; u < 8; ++u)
#pragma unroll
      for (int o = 0; o < 64; ++o) z[o] = fmaf(PT[(c0 + u) * 64 + o], xc[u], z[o]);
  }
  float m = 0.f;
#pragma unroll
  for (int o = 0; o < 64; ++o) m += z[o];
  m *= (1.0f / 64.0f);
  float v = 0.f;
#pragma unroll
  for (int o = 0; o < 64; ++o) { float d = z[o] - m; v = fmaf(d, d, v); }
  v *= (1.0f / 64.0f);
  float r = rsqrtf(v + EPS_);
  float* y2 = dout + ((size_t)b * CCH + HCH) * NN;
#pragma unroll
  for (int o = 0; o < 64; ++o)
    y2[(size_t)o * NN + n] = (z[o] - m) * r * g2[o] + b2[o];
}

// CG[b] = X1 @ Y2^T  (y2 read back from dout)
__global__ __launch_bounds__(256) void k_cgram(const float* __restrict__ x,
                                               const float* __restrict__ dout,
                                               float* __restrict__ ws) {
  __shared__ float x1t[64 * LSTR];
  __shared__ float y2t[64 * LSTR];
  const int tid = threadIdx.x;
  const int b = blockIdx.y;
  const int ti = tid & 15, tj = tid >> 4;
  const float* x1p = x + (size_t)b * CCH * NN;
  const float* y2p = dout + ((size_t)b * CCH + HCH) * NN;

  float acc[4][4];
#pragma unroll
  for (int a = 0; a < 4; ++a)
#pragma unroll
    for (int c = 0; c < 4; ++c) acc[a][c] = 0.f;

  for (int t = blockIdx.x; t < NN / 64; t += gridDim.x) {
    const int base = t * 64;
    for (int i = tid; i < 64 * 64; i += 256) {
      int ch = i >> 6, p = i & 63;
      x1t[p * LSTR + ch] = x1p[(size_t)ch * NN + base + p];
      y2t[p * LSTR + ch] = y2p[(size_t)ch * NN + base + p];
    }
    __syncthreads();
    for (int p = 0; p < 64; ++p) {
      float av[4], bv[4];
#pragma unroll
      for (int a = 0; a < 4; ++a) av[a] = x1t[p * LSTR + 4 * ti + a];
#pragma unroll
      for (int c = 0; c < 4; ++c) bv[c] = y2t[p * LSTR + 4 * tj + c];
#pragma unroll
      for (int a = 0; a < 4; ++a)
#pragma unroll
        for (int c = 0; c < 4; ++c) acc[a][c] = fmaf(av[a], bv[c], acc[a][c]);
    }
    __syncthreads();
  }
  float* CG = ws + OFF_CG + b * 4096;
#pragma unroll
  for (int a = 0; a < 4; ++a)
#pragma unroll
    for (int c = 0; c < 4; ++c)
      atomicAdd(&CG[(4 * ti + a) * 64 + (4 * tj + c)], acc[a][c]);
}

// per pixel: c = cattn@y2 ; x1g = x1*(1+sigmoid(c)) ; y1 = LN(W1@x1g) -> dout ch 0..63
__global__ __launch_bounds__(256) void f_y1(const float* __restrict__ x,
                                            const float* __restrict__ ws,
                                            const float* __restrict__ g1,
                                            const float* __restrict__ b1,
                                            float* __restrict__ dout) {
  const int tid = threadIdx.x;
  const int b = blockIdx.y;
  const int n = blockIdx.x * 256 + tid;
  const float* CT  = ws + OFF_CAT + b * 4096;
  const float* W1T = ws + OFF_W1T;
  const float* x1p = x + (size_t)b * CCH * NN;
  const float* y2p = dout + ((size_t)b * CCH + HCH) * NN;

  float cacc[64];
#pragma unroll
  for (int q = 0; q < 64; ++q) cacc[q] = 0.f;
#pragma unroll
  for (int k0 = 0; k0 < 64; k0 += 8) {
    float yk[8];
#pragma unroll
    for (int u = 0; u < 8; ++u) yk[u] = y2p[(size_t)(k0 + u) * NN + n];
#pragma unroll
    for (int u = 0; u < 8; ++u)
#pragma unroll
      for (int q = 0; q < 64; ++q) cacc[q] = fmaf(CT[(k0 + u) * 64 + q], yk[u], cacc[q]);
  }
  float w1[64];
#pragma unroll
  for (int o = 0; o < 64; ++o) w1[o] = 0.f;
#pragma unroll
  for (int c0 = 0; c0 < 64; c0 += 8) {
    float xv[8];
#pragma unroll
    for (int u = 0; u < 8; ++u) xv[u] = x1p[(size_t)(c0 + u) * NN + n];
#pragma unroll
    for (int u = 0; u < 8; ++u) {
      float cr = 1.0f / (1.0f + __expf(-cacc[c0 + u]));
      float xg = xv[u] + xv[u] * cr;
#pragma unroll
      for (int o = 0; o < 64; ++o) w1[o] = fmaf(W1T[(c0 + u) * 64 + o], xg, w1[o]);
    }
  }
  float m = 0.f;
#pragma unroll
  for (int o = 0; o < 64; ++o) m += w1[o];
  m *= (1.0f / 64.0f);
  float v = 0.f;
#pragma unroll
  for (int o = 0; o < 64; ++o) { float d = w1[o] - m; v = fmaf(d, d, v); }
  v *= (1.0f / 64.0f);
  float r = rsqrtf(v + EPS_);
  float* y1 = dout + (size_t)b * CCH * NN;
#pragma unroll
  for (int o = 0; o < 64; ++o)
    y1[(size_t)o * NN + n] = (w1[o] - m) * r * g1[o] + b1[o];
}

// out = relu(LN128(Wo @ [y1;y2])) + x.  2 lanes per pixel (halves of the 128
// outputs); LN-128 reduce via shfl_xor(32). Pixel-local overwrite of dout.
__global__ __launch_bounds__(256) void f_out(const float* __restrict__ x,
                                             const float* __restrict__ ws,
                                             const float* __restrict__ go,
                                             const float* __restrict__ bo,
                                             float* __restrict__ dout) {
  const int tid = threadIdx.x;
  const int b = blockIdx.y;
  const int lane = tid & 63;
  const int wv = tid >> 6;
  const int half = lane >> 5;
  const int p = blockIdx.x * 128 + wv * 32 + (lane & 31);
  const float* WOT = ws + OFF_WOT;                  // [c][o]
  const float* mrg = dout + (size_t)b * CCH * NN;   // [y1;y2] channels 0..127
  const float* xb  = x + (size_t)b * CCH * NN;

  float t[64];
#pragma unroll
  for (int j = 0; j < 64; ++j) t[j] = 0.f;
#pragma unroll
  for (int c0 = 0; c0 < 128; c0 += 8) {
    float mv[8];
#pragma unroll
    for (int u = 0; u < 8; ++u) mv[u] = mrg[(size_t)(c0 + u) * NN + p];
#pragma unroll
    for (int u = 0; u < 8; ++u)
#pragma unroll
      for (int j = 0; j < 64; ++j)
        t[j] = fmaf(WOT[(c0 + u) * 128 + half * 64 + j], mv[u], t[j]);
  }
  float s = 0.f;
#pragma unroll
  for (int j = 0; j < 64; ++j) s += t[j];
  s += __shfl_xor(s, 32, 64);
  float m = s * (1.0f / 128.0f);
  float v = 0.f;
#pragma unroll
  for (int j = 0; j < 64; ++j) { float d = t[j] - m; v = fmaf(d, d, v); }
  v += __shfl_xor(v, 32, 64);
  v *= (1.0f / 128.0f);
  float r = rsqrtf(v + EPS_);
  const int co = half * 64;
#pragma unroll
  for (int j = 0; j < 64; ++j) {
    float val = (t[j] - m) * r * go[co + j] + bo[co + j];
    val = fmaxf(val, 0.0f);
    dout[(size_t)b * CCH * NN + (size_t)(co + j) * NN + p] =
        val + xb[(size_t)(co + j) * NN + p];
  }
}

// ---------------------------------------------------------------- launch

extern "C" void kernel_launch(void* const* d_in, const int* in_sizes, int n_in,
                              void* d_out, int out_size, void* d_ws, size_t ws_size,
                              hipStream_t stream) {
  (void)in_sizes; (void)n_in; (void)out_size; (void)ws_size;
  const float* x      = (const float*)d_in[0];
  const float* ln1_w  = (const float*)d_in[1];
  const float* ln2_w  = (const float*)d_in[2];
  const float* out1_w = (const float*)d_in[3];
  const float* out1_g = (const float*)d_in[4];
  const float* out1_b = (const float*)d_in[5];
  const float* out2_w = (const float*)d_in[6];
  const float* out2_g = (const float*)d_in[7];
  const float* out2_b = (const float*)d_in[8];
  const float* out_w  = (const float*)d_in[9];
  const float* out_g  = (const float*)d_in[10];
  const float* out_b  = (const float*)d_in[11];
  float* dout = (float*)d_out;
  float* ws   = (float*)d_ws;

  // zero the two atomically-accumulated regions (G, CG)
  hipMemsetAsync(d_ws, 0, (size_t)OFF_PT * sizeof(float), stream);

  hipLaunchKernelGGL(k_transpose, dim3(16), dim3(256), 0, stream, out1_w, out_w, ws);
  hipLaunchKernelGGL(k_gram,  dim3(128, BB), dim3(256), 0, stream, x, ws);
  hipLaunchKernelGGL(k_attn,  dim3(BB), dim3(256), 0, stream, ln2_w, out2_w, ws);
  hipLaunchKernelGGL(f_y2,    dim3(NN / 256, BB), dim3(256), 0, stream,
                     x, ws, out2_g, out2_b, dout);
  hipLaunchKernelGGL(k_cgram, dim3(256, BB), dim3(256), 0, stream, x, dout, ws);
  hipLaunchKernelGGL(k_cattn, dim3(BB), dim3(256), 0, stream, ln1_w, ws);
  hipLaunchKernelGGL(f_y1,    dim3(NN / 256, BB), dim3(256), 0, stream,
                     x, ws, out1_g, out1_b, dout);
  hipLaunchKernelGGL(f_out,   dim3(NN / 128, BB), dim3(256), 0, stream,
                     x, ws, out_g, out_b, dout);
}

// Round 8
// 947.618 us; speedup vs baseline: 1.8390x; 1.3525x over previous
//
#include <hip/hip_runtime.h>
#include <math.h>

// Problem constants
#define BB  4
#define CCH 128
#define HCH 64
#define NN  65536            // H*W

constexpr float EPS_   = 1e-5f;
constexpr float SCALE_ = 1.0f / 4194304.0f;   // 1/(N*HC), exact pow2

#define LSTR 65              // odd LDS row stride -> conflict-free staging writes

// workspace layout (float offsets) -- only small matrices live in ws now
#define OFF_G    0           // [B][64][64]  Gram of x2          (zeroed, atomic)
#define OFF_CG   16384       // [B][64][64]  cross-Gram X1*Y2^T  (zeroed, atomic)
#define OFF_PT   32768       // [B][64][64]  P^T  (PT[c*64+o] = P[o][c])
#define OFF_CAT  49152       // [B][64][64]  cattn^T (CT[k*64+q] = cattn[q][k])
#define OFF_W1T  65536       // [64][64]     out1_w^T  ([c][o])
#define OFF_WOT  69632       // [128][128]   out_w^T   ([c][o])

// y2 lives in d_out channels 64..127; y1 in d_out channels 0..63 (pixel-local
// overwrite in f_out is race-free: reads complete before barrier 1, writes
// happen after barrier 2, and each pixel is owned by one wave pair in one block).

// ---------------------------------------------------------------- helpers

__device__ __forceinline__ void softmax_row64(float* row) {
  float mx = -1e30f;
  for (int k = 0; k < 64; ++k) mx = fmaxf(mx, row[k] * SCALE_);
  float s = 0.f;
  for (int k = 0; k < 64; ++k) {
    float e = __expf(row[k] * SCALE_ - mx);
    row[k] = e;
    s += e;
  }
  float inv = 1.0f / s;
  for (int k = 0; k < 64; ++k) row[k] *= inv;
}

__device__ __forceinline__ void mm64_nn(const float* A, const float* Bm, float* Co,
                                        int ti, int tj) {
  float acc[4][4];
#pragma unroll
  for (int a = 0; a < 4; ++a)
#pragma unroll
    for (int c = 0; c < 4; ++c) acc[a][c] = 0.f;
  for (int m = 0; m < 64; ++m) {
    float av[4], bv[4];
#pragma unroll
    for (int a = 0; a < 4; ++a) av[a] = A[(4 * ti + a) * LSTR + m];
#pragma unroll
    for (int c = 0; c < 4; ++c) bv[c] = Bm[m * LSTR + 4 * tj + c];
#pragma unroll
    for (int a = 0; a < 4; ++a)
#pragma unroll
      for (int c = 0; c < 4; ++c) acc[a][c] = fmaf(av[a], bv[c], acc[a][c]);
  }
#pragma unroll
  for (int a = 0; a < 4; ++a)
#pragma unroll
    for (int c = 0; c < 4; ++c) Co[(4 * ti + a) * LSTR + 4 * tj + c] = acc[a][c];
}

__device__ __forceinline__ void mm64_nt(const float* A, const float* Bm, float* Co,
                                        int ti, int tj) {
  float acc[4][4];
#pragma unroll
  for (int a = 0; a < 4; ++a)
#pragma unroll
    for (int c = 0; c < 4; ++c) acc[a][c] = 0.f;
  for (int m = 0; m < 64; ++m) {
    float av[4], bv[4];
#pragma unroll
    for (int a = 0; a < 4; ++a) av[a] = A[(4 * ti + a) * LSTR + m];
#pragma unroll
    for (int c = 0; c < 4; ++c) bv[c] = Bm[(4 * tj + c) * LSTR + m];
#pragma unroll
    for (int a = 0; a < 4; ++a)
#pragma unroll
      for (int c = 0; c < 4; ++c) acc[a][c] = fmaf(av[a], bv[c], acc[a][c]);
  }
#pragma unroll
  for (int a = 0; a < 4; ++a)
#pragma unroll
    for (int c = 0; c < 4; ++c) Co[(4 * ti + a) * LSTR + 4 * tj + c] = acc[a][c];
}

__device__ __forceinline__ void ld64(float* dst, const float* src, int tid) {
  for (int i = tid; i < 4096; i += 256) dst[(i >> 6) * LSTR + (i & 63)] = src[i];
}

// ---------------------------------------------------------------- small kernels

__global__ void k_transpose(const float* __restrict__ w1,
                            const float* __restrict__ wo,
                            float* __restrict__ ws) {
  int tid = blockIdx.x * blockDim.x + threadIdx.x;
  int stride = gridDim.x * blockDim.x;
  for (int i = tid; i < 64 * 64; i += stride) {
    int o = i >> 6, c = i & 63;
    ws[OFF_W1T + c * 64 + o] = w1[o * 64 + c];
  }
  for (int i = tid; i < 128 * 128; i += stride) {
    int o = i >> 7, c = i & 127;
    ws[OFF_WOT + c * 128 + o] = wo[o * 128 + c];
  }
}

// G[b] = X2_b @ X2_b^T
__global__ __launch_bounds__(256) void k_gram(const float* __restrict__ x,
                                              float* __restrict__ ws) {
  __shared__ float tile[128 * LSTR];
  const int tid = threadIdx.x;
  const int b = blockIdx.y;
  const int ti = tid & 15, tj = tid >> 4;
  const float* x2 = x + ((size_t)b * CCH + HCH) * NN;

  float acc[4][4];
#pragma unroll
  for (int a = 0; a < 4; ++a)
#pragma unroll
    for (int c = 0; c < 4; ++c) acc[a][c] = 0.f;

  for (int t = blockIdx.x; t < NN / 128; t += gridDim.x) {
    const int base = t * 128;
    for (int i = tid; i < 128 * 64; i += 256) {
      int ch = i >> 7, p = i & 127;
      tile[p * LSTR + ch] = x2[(size_t)ch * NN + base + p];
    }
    __syncthreads();
    for (int p = 0; p < 128; ++p) {
      float av[4], bv[4];
#pragma unroll
      for (int a = 0; a < 4; ++a) av[a] = tile[p * LSTR + 4 * ti + a];
#pragma unroll
      for (int c = 0; c < 4; ++c) bv[c] = tile[p * LSTR + 4 * tj + c];
#pragma unroll
      for (int a = 0; a < 4; ++a)
#pragma unroll
        for (int c = 0; c < 4; ++c) acc[a][c] = fmaf(av[a], bv[c], acc[a][c]);
    }
    __syncthreads();
  }
  float* G = ws + OFF_G + b * 4096;
#pragma unroll
  for (int a = 0; a < 4; ++a)
#pragma unroll
    for (int c = 0; c < 4; ++c)
      atomicAdd(&G[(4 * ti + a) * 64 + (4 * tj + c)], acc[a][c]);
}

// per batch: S = Wq G Wk^T ; attn = softmax ; M = attn Wv ; P = O2a + O2b M ; store P^T
__global__ __launch_bounds__(256) void k_attn(const float* __restrict__ ln2_w,
                                              const float* __restrict__ out2_w,
                                              float* __restrict__ ws) {
  __shared__ float LA[64 * LSTR], LB[64 * LSTR], LC[64 * LSTR];
  const int b = blockIdx.x, tid = threadIdx.x;
  const int ti = tid & 15, tj = tid >> 4;
  const float* G = ws + OFF_G + b * 4096;

  ld64(LA, ln2_w, tid);              // Wq
  ld64(LB, G, tid);
  __syncthreads();
  mm64_nn(LA, LB, LC, ti, tj);       // LC = Wq @ G
  __syncthreads();
  ld64(LA, ln2_w + 4096, tid);       // Wk
  __syncthreads();
  mm64_nt(LC, LA, LB, ti, tj);       // LB = S
  __syncthreads();
  if (tid < 64) softmax_row64(LB + tid * LSTR);
  __syncthreads();
  ld64(LA, ln2_w + 8192, tid);       // Wv
  __syncthreads();
  mm64_nn(LB, LA, LC, ti, tj);       // LC = attn @ Wv
  __syncthreads();
  for (int i = tid; i < 4096; i += 256)            // LA = O2b
    LA[(i >> 6) * LSTR + (i & 63)] = out2_w[(i >> 6) * 128 + 64 + (i & 63)];
  __syncthreads();
  float* PT = ws + OFF_PT + b * 4096;
#pragma unroll
  for (int a = 0; a < 4; ++a) {
#pragma unroll
    for (int c = 0; c < 4; ++c) {
      int o = 4 * ti + a, j = 4 * tj + c;
      float s = out2_w[o * 128 + j];               // O2a
      for (int m = 0; m < 64; ++m) s = fmaf(LA[o * LSTR + m], LC[m * LSTR + j], s);
      PT[j * 64 + o] = s;
    }
  }
}

// per batch: T = W1 @ CG ; cattn = softmax ; store cattn^T
__global__ __launch_bounds__(256) void k_cattn(const float* __restrict__ ln1_w,
                                               float* __restrict__ ws) {
  __shared__ float LA[64 * LSTR], LB[64 * LSTR], LC[64 * LSTR];
  const int b = blockIdx.x, tid = threadIdx.x;
  const int ti = tid & 15, tj = tid >> 4;
  ld64(LA, ln1_w, tid);
  ld64(LB, ws + OFF_CG + b * 4096, tid);
  __syncthreads();
  mm64_nn(LA, LB, LC, ti, tj);
  __syncthreads();
  if (tid < 64) softmax_row64(LC + tid * LSTR);
  __syncthreads();
  float* CT = ws + OFF_CAT + b * 4096;
  for (int i = tid; i < 4096; i += 256) {
    int q = i >> 6, k = i & 63;
    CT[k * 64 + q] = LC[q * LSTR + k];
  }
}

// ---------------------------------------------------------------- streaming kernels

// y2 = LN(P @ x2) per pixel -> dout channels 64..127
__global__ __launch_bounds__(256) void f_y2(const float* __restrict__ x,
                                            const float* __restrict__ ws,
                                            const float* __restrict__ g2,
                                            const float* __restrict__ b2,
                                            float* __restrict__ dout) {
  const int tid = threadIdx.x;
  const int b = blockIdx.y;
  const int n = blockIdx.x * 256 + tid;
  const float* PT  = ws + OFF_PT + b * 4096;
  const float* x2p = x + ((size_t)b * CCH + HCH) * NN;

  float z[64];
#pragma unroll
  for (int o = 0; o < 64; ++o) z[o] = 0.f;
#pragma unroll
  for (int c0 = 0; c0 < 64; c0 += 8) {
    float xc[8];
#pragma unroll
    for (int u = 0; u < 8; ++u) xc[u] = x2p[(size_t)(c0 + u) * NN + n];
#pragma unroll
    for (int u = 0; u < 8; ++u)
#pragma unroll
      for (int o = 0; o < 64; ++o) z[o] = fmaf(PT[(c0 + u) * 64 + o], xc[u], z[o]);
  }
  float m = 0.f;
#pragma unroll
  for (int o = 0; o < 64; ++o) m += z[o];
  m *= (1.0f / 64.0f);
  float v = 0.f;
#pragma unroll
  for (int o = 0; o < 64; ++o) { float d = z[o] - m; v = fmaf(d, d, v); }
  v *= (1.0f / 64.0f);
  float r = rsqrtf(v + EPS_);
  float* y2 = dout + ((size_t)b * CCH + HCH) * NN;
#pragma unroll
  for (int o = 0; o < 64; ++o)
    y2[(size_t)o * NN + n] = (z[o] - m) * r * g2[o] + b2[o];
}

// CG[b] = X1 @ Y2^T  (y2 read back from dout)
__global__ __launch_bounds__(256) void k_cgram(const float* __restrict__ x,
                                               const float* __restrict__ dout,
                                               float* __restrict__ ws) {
  __shared__ float x1t[64 * LSTR];
  __shared__ float y2t[64 * LSTR];
  const int tid = threadIdx.x;
  const int b = blockIdx.y;
  const int ti = tid & 15, tj = tid >> 4;
  const float* x1p = x + (size_t)b * CCH * NN;
  const float* y2p = dout + ((size_t)b * CCH + HCH) * NN;

  float acc[4][4];
#pragma unroll
  for (int a = 0; a < 4; ++a)
#pragma unroll
    for (int c = 0; c < 4; ++c) acc[a][c] = 0.f;

  for (int t = blockIdx.x; t < NN / 64; t += gridDim.x) {
    const int base = t * 64;
    for (int i = tid; i < 64 * 64; i += 256) {
      int ch = i >> 6, p = i & 63;
      x1t[p * LSTR + ch] = x1p[(size_t)ch * NN + base + p];
      y2t[p * LSTR + ch] = y2p[(size_t)ch * NN + base + p];
    }
    __syncthreads();
    for (int p = 0; p < 64; ++p) {
      float av[4], bv[4];
#pragma unroll
      for (int a = 0; a < 4; ++a) av[a] = x1t[p * LSTR + 4 * ti + a];
#pragma unroll
      for (int c = 0; c < 4; ++c) bv[c] = y2t[p * LSTR + 4 * tj + c];
#pragma unroll
      for (int a = 0; a < 4; ++a)
#pragma unroll
        for (int c = 0; c < 4; ++c) acc[a][c] = fmaf(av[a], bv[c], acc[a][c]);
    }
    __syncthreads();
  }
  float* CG = ws + OFF_CG + b * 4096;
#pragma unroll
  for (int a = 0; a < 4; ++a)
#pragma unroll
    for (int c = 0; c < 4; ++c)
      atomicAdd(&CG[(4 * ti + a) * 64 + (4 * tj + c)], acc[a][c]);
}

// per pixel: c = cattn@y2 ; x1g = x1*(1+sigmoid(c)) ; y1 = LN(W1@x1g) -> dout ch 0..63
__global__ __launch_bounds__(256) void f_y1(const float* __restrict__ x,
                                            const float* __restrict__ ws,
                                            const float* __restrict__ g1,
                                            const float* __restrict__ b1,
                                            float* __restrict__ dout) {
  const int tid = threadIdx.x;
  const int b = blockIdx.y;
  const int n = blockIdx.x * 256 + tid;
  const float* CT  = ws + OFF_CAT + b * 4096;
  const float* W1T = ws + OFF_W1T;
  const float* x1p = x + (size_t)b * CCH * NN;
  const float* y2p = dout + ((size_t)b * CCH + HCH) * NN;

  float cacc[64];
#pragma unroll
  for (int q = 0; q < 64; ++q) cacc[q] = 0.f;
#pragma unroll
  for (int k0 = 0; k0 < 64; k0 += 8) {
    float yk[8];
#pragma unroll
    for (int u = 0; u < 8; ++u) yk[u] = y2p[(size_t)(k0 + u) * NN + n];
#pragma unroll
    for (int u = 0; u < 8; ++u)
#pragma unroll
      for (int q = 0; q < 64; ++q) cacc[q] = fmaf(CT[(k0 + u) * 64 + q], yk[u], cacc[q]);
  }
  float w1[64];
#pragma unroll
  for (int o = 0; o < 64; ++o) w1[o] = 0.f;
#pragma unroll
  for (int c0 = 0; c0 < 64; c0 += 8) {
    float xv[8];
#pragma unroll
    for (int u = 0; u < 8; ++u) xv[u] = x1p[(size_t)(c0 + u) * NN + n];
#pragma unroll
    for (int u = 0; u < 8; ++u) {
      float cr = 1.0f / (1.0f + __expf(-cacc[c0 + u]));
      float xg = xv[u] + xv[u] * cr;
#pragma unroll
      for (int o = 0; o < 64; ++o) w1[o] = fmaf(W1T[(c0 + u) * 64 + o], xg, w1[o]);
    }
  }
  float m = 0.f;
#pragma unroll
  for (int o = 0; o < 64; ++o) m += w1[o];
  m *= (1.0f / 64.0f);
  float v = 0.f;
#pragma unroll
  for (int o = 0; o < 64; ++o) { float d = w1[o] - m; v = fmaf(d, d, v); }
  v *= (1.0f / 64.0f);
  float r = rsqrtf(v + EPS_);
  float* y1 = dout + (size_t)b * CCH * NN;
#pragma unroll
  for (int o = 0; o < 64; ++o)
    y1[(size_t)o * NN + n] = (w1[o] - m) * r * g1[o] + b1[o];
}

// out = relu(LN128(Wo @ [y1;y2])) + x.
// WAVE-UNIFORM half: waves {0,1} share pixel group 0 (halves 0,1), waves {2,3}
// share group 1. Weight addresses = uniform base + compile-time offset -> s_load
// (scalar pipe), eliminating the 8192 per-lane VMEM ops that made the previous
// version latency-bound (VALUBusy 12.6%). LN-128 reduced across the wave pair
// via a small LDS exchange.
__global__ __launch_bounds__(256) void f_out(const float* __restrict__ x,
                                             const float* __restrict__ ws,
                                             const float* __restrict__ go,
                                             const float* __restrict__ bo,
                                             float* __restrict__ dout) {
  __shared__ float red_s[2][2][64];
  __shared__ float red_v[2][2][64];
  const int tid  = threadIdx.x;
  const int b    = blockIdx.y;
  const int lane = tid & 63;
  const int grp  = (tid >> 7) & 1;                          // wave pair id
  const int half = __builtin_amdgcn_readfirstlane((tid >> 6) & 1);  // SGPR
  const int p    = blockIdx.x * 128 + grp * 64 + lane;
  const float* WOT = ws + OFF_WOT + half * 64;      // [c][128] offset to our half
  const float* mrg = dout + (size_t)b * CCH * NN;   // [y1;y2] channels 0..127
  const float* xb  = x + (size_t)b * CCH * NN;

  float t[64];
#pragma unroll
  for (int j = 0; j < 64; ++j) t[j] = 0.f;
#pragma unroll
  for (int c0 = 0; c0 < 128; c0 += 8) {
    float mv[8];
#pragma unroll
    for (int u = 0; u < 8; ++u) mv[u] = mrg[(size_t)(c0 + u) * NN + p];
#pragma unroll
    for (int u = 0; u < 8; ++u)
#pragma unroll
      for (int j = 0; j < 64; ++j)
        t[j] = fmaf(WOT[(c0 + u) * 128 + j], mv[u], t[j]);
  }
  float s = 0.f;
#pragma unroll
  for (int j = 0; j < 64; ++j) s += t[j];
  red_s[grp][half][lane] = s;
  __syncthreads();
  float m = (s + red_s[grp][1 - half][lane]) * (1.0f / 128.0f);
  float v = 0.f;
#pragma unroll
  for (int j = 0; j < 64; ++j) { float d = t[j] - m; v = fmaf(d, d, v); }
  red_v[grp][half][lane] = v;
  __syncthreads();
  v = (v + red_v[grp][1 - half][lane]) * (1.0f / 128.0f);
  float r = rsqrtf(v + EPS_);
  const int co = half * 64;
#pragma unroll
  for (int j = 0; j < 64; ++j) {
    float val = (t[j] - m) * r * go[co + j] + bo[co + j];
    val = fmaxf(val, 0.0f);
    dout[(size_t)b * CCH * NN + (size_t)(co + j) * NN + p] =
        val + xb[(size_t)(co + j) * NN + p];
  }
}

// ---------------------------------------------------------------- launch

extern "C" void kernel_launch(void* const* d_in, const int* in_sizes, int n_in,
                              void* d_out, int out_size, void* d_ws, size_t ws_size,
                              hipStream_t stream) {
  (void)in_sizes; (void)n_in; (void)out_size; (void)ws_size;
  const float* x      = (const float*)d_in[0];
  const float* ln1_w  = (const float*)d_in[1];
  const float* ln2_w  = (const float*)d_in[2];
  const float* out1_w = (const float*)d_in[3];
  const float* out1_g = (const float*)d_in[4];
  const float* out1_b = (const float*)d_in[5];
  const float* out2_w = (const float*)d_in[6];
  const float* out2_g = (const float*)d_in[7];
  const float* out2_b = (const float*)d_in[8];
  const float* out_w  = (const float*)d_in[9];
  const float* out_g  = (const float*)d_in[10];
  const float* out_b  = (const float*)d_in[11];
  float* dout = (float*)d_out;
  float* ws   = (float*)d_ws;

  // zero the two atomically-accumulated regions (G, CG)
  hipMemsetAsync(d_ws, 0, (size_t)OFF_PT * sizeof(float), stream);

  hipLaunchKernelGGL(k_transpose, dim3(16), dim3(256), 0, stream, out1_w, out_w, ws);
  hipLaunchKernelGGL(k_gram,  dim3(128, BB), dim3(256), 0, stream, x, ws);
  hipLaunchKernelGGL(k_attn,  dim3(BB), dim3(256), 0, stream, ln2_w, out2_w, ws);
  hipLaunchKernelGGL(f_y2,    dim3(NN / 256, BB), dim3(256), 0, stream,
                     x, ws, out2_g, out2_b, dout);
  hipLaunchKernelGGL(k_cgram, dim3(256, BB), dim3(256), 0, stream, x, dout, ws);
  hipLaunchKernelGGL(k_cattn, dim3(BB), dim3(256), 0, stream, ln1_w, ws);
  hipLaunchKernelGGL(f_y1,    dim3(NN / 256, BB), dim3(256), 0, stream,
                     x, ws, out1_g, out1_b, dout);
  hipLaunchKernelGGL(f_out,   dim3(NN / 128, BB), dim3(256), 0, stream,
                     x, ws, out_g, out_b, dout);
}